// Round 7
// baseline (569.087 us; speedup 1.0000x reference)
//
#include <hip/hip_runtime.h>

// Problem constants (B=1)
constexpr int Cc = 32;
constexpr int Dd = 48;
constexpr int Hh = 96;
constexpr int Ww = 192;
constexpr int TW = 16;           // W-kernel tile width
constexpr int NT = Ww / TW;      // 12 tiles
constexpr float NEGBIG = -3.402823466e+38f;

// ---- DPP helpers (W kernel) -------------------------------------------------
// NOTE: must use __builtin_amdgcn_update_dpp (not inline asm) — the compiler's
// hazard recognizer inserts the required VALU->DPP wait states only for
// compiler-known DPP ops. Inline-asm DPP caused silent corruption (round 3).
template <int CTRL, int RM>
__device__ __forceinline__ float dppmov(float v) {
    int i = __builtin_bit_cast(int, v);
    int r = __builtin_amdgcn_update_dpp(i, i, CTRL, RM, 0xF, false);
    return __builtin_bit_cast(float, r);
}

__device__ __forceinline__ float rdlane(float v, int idx) {
    int r = __builtin_amdgcn_readlane(__builtin_bit_cast(int, v), idx);
    return __builtin_bit_cast(float, r);
}

__device__ __forceinline__ unsigned f2h(float v) {
    return (unsigned)__builtin_bit_cast(unsigned short, (_Float16)v);
}
__device__ __forceinline__ float h2f(unsigned short u) {
    return (float)__builtin_bit_cast(_Float16, u);
}

// Max over lanes 0..47, broadcast. Row-confined: junk in lanes 48..63 never
// enters the reduction.
__device__ __forceinline__ float wave_max48(float v) {
    v = fmaxf(v, dppmov<0x111, 0xF>(v));   // row_shr:1
    v = fmaxf(v, dppmov<0x112, 0xF>(v));   // row_shr:2
    v = fmaxf(v, dppmov<0x114, 0xF>(v));   // row_shr:4
    v = fmaxf(v, dppmov<0x118, 0xF>(v));   // row_shr:8
    v = fmaxf(v, dppmov<0x142, 0x2>(v));   // row_bcast:15 -> row1: lane31=max(0..31)
    v = fmaxf(v, dppmov<0x143, 0x4>(v));   // row_bcast:31 -> row2: lane47=max(0..47)
    return rdlane(v, 47);
}

// One SGA step (lane = d form, W kernel).
__device__ __forceinline__ float sga_step(float A, float cs, float g0v, float g1v, float g2v,
                                          float g3v, float g4v, bool is47, bool first) {
    float dm1 = dppmov<0x138, 0xF>(A);             // wave_shr:1, lane0 keeps own
    float dp1 = dppmov<0x130, 0xF>(A);             // wave_shl:1
    dp1 = is47 ? A : dp1;                          // d+1 clamp at d=47
    float mx = wave_max48(A);
    float r = g0v * cs + g1v * A + g2v * dm1 + g3v * dp1 + g4v * mx;
    return first ? cs : r;
}

// ============================================================================
// W-pair kernel (unchanged from round 6): fwd scan (ga) stashes a0 fp16
// on-chip, rev scan (gb) combines (+ ws), writes out once. 1 wave/block.
// ============================================================================
template <bool WS>
__global__ __launch_bounds__(64, 4) void sga_w4(const float* __restrict__ x,
                                                const float* __restrict__ ga,
                                                const float* __restrict__ gb,
                                                float* __restrict__ out,
                                                const unsigned* __restrict__ ws) {
    __shared__ unsigned sstash[64][Dd];   // tiles 0..7, [t*8+r][lane]
    __shared__ float xo[Dd][TW + 1];      // x tile / flush tile

    const int bid = blockIdx.x;
    const int c = bid / Hh;
    const int h = bid - c * Hh;
    const int lane = threadIdx.x;
    const size_t HW = (size_t)Hh * Ww;

    const float* xrow = x + (size_t)c * Dd * HW + (size_t)h * Ww;
    const float* garow = ga + (size_t)c * 5 * HW + (size_t)h * Ww;
    const float* gbrow = gb + (size_t)c * 5 * HW + (size_t)h * Ww;
    float* orow = out + (size_t)c * Dd * HW + (size_t)h * Ww;
    const size_t wsrow = ((size_t)c * Hh + h) * Dd;   // in 96-u32 rows

    const int dl = (lane < Dd) ? lane : (Dd - 1);
    const bool is47 = (lane == Dd - 1);

    int srow[3], scol[3];
#pragma unroll
    for (int i = 0; i < 3; ++i) {
        const int e4 = lane + i * 64;
        srow[i] = e4 >> 2;
        scol[i] = (e4 & 3) * 4;
    }
    const int gk = lane >> 4;
    const int gwi = lane & 15;

    float4 pre[3];
    float gA, g4r, gAn = 0.f, g4n = 0.f;
    unsigned tr[8];
    unsigned sv0[8], sv1[8], sv2[8], sv3[8];

    {
#pragma unroll
        for (int i = 0; i < 3; ++i)
            pre[i] = *reinterpret_cast<const float4*>(xrow + (size_t)srow[i] * HW + scol[i]);
        gA = garow[(size_t)gk * HW + gwi];
        g4r = garow[(size_t)4 * HW + gwi];
#pragma unroll
        for (int i = 0; i < 3; ++i) {
            xo[srow[i]][scol[i] + 0] = pre[i].x;
            xo[srow[i]][scol[i] + 1] = pre[i].y;
            xo[srow[i]][scol[i] + 2] = pre[i].z;
            xo[srow[i]][scol[i] + 3] = pre[i].w;
        }
    }

    float A = NEGBIG;

    // forward: a0 -> on-chip fp16 stash
    for (int t = 0; t < NT; ++t) {
        if (t + 1 < NT) {
            const int wn = (t + 1) * TW;
#pragma unroll
            for (int i = 0; i < 3; ++i)
                pre[i] = *reinterpret_cast<const float4*>(xrow + (size_t)srow[i] * HW + wn + scol[i]);
            gAn = garow[(size_t)gk * HW + wn + gwi];
            g4n = garow[(size_t)4 * HW + wn + gwi];
        }
#pragma unroll
        for (int wk = 0; wk < TW; ++wk) {
            const float g0v = rdlane(gA, wk);
            const float g1v = rdlane(gA, 16 + wk);
            const float g2v = rdlane(gA, 32 + wk);
            const float g3v = rdlane(gA, 48 + wk);
            const float g4v = rdlane(g4r, wk);
            const float cs = xo[dl][wk];
            A = sga_step(A, cs, g0v, g1v, g2v, g3v, g4v, is47, (t == 0 && wk == 0));
            const unsigned hu = f2h(A);
            if ((wk & 1) == 0) tr[wk >> 1] = hu;
            else tr[wk >> 1] |= hu << 16;
        }
        if (t < 8) {
            if (lane < Dd) {
#pragma unroll
                for (int r = 0; r < 8; ++r) sstash[t * 8 + r][lane] = tr[r];
            }
        } else if (t == 8) {
#pragma unroll
            for (int r = 0; r < 8; ++r) sv0[r] = tr[r];
        } else if (t == 9) {
#pragma unroll
            for (int r = 0; r < 8; ++r) sv1[r] = tr[r];
        } else if (t == 10) {
#pragma unroll
            for (int r = 0; r < 8; ++r) sv2[r] = tr[r];
        } else {
#pragma unroll
            for (int r = 0; r < 8; ++r) sv3[r] = tr[r];
        }
        if (t + 1 < NT) {
#pragma unroll
            for (int i = 0; i < 3; ++i) {
                xo[srow[i]][scol[i] + 0] = pre[i].x;
                xo[srow[i]][scol[i] + 1] = pre[i].y;
                xo[srow[i]][scol[i] + 2] = pre[i].z;
                xo[srow[i]][scol[i] + 3] = pre[i].w;
            }
            gA = gAn;
            g4r = g4n;
        }
    }

    // reverse + combine + single write
    A = NEGBIG;
    unsigned wsc[6], wsn[6];
    {
        const int w0 = (NT - 1) * TW;
        gA = gbrow[(size_t)gk * HW + w0 + gwi];
        g4r = gbrow[(size_t)4 * HW + w0 + gwi];
        if constexpr (WS) {
#pragma unroll
            for (int i = 0; i < 3; ++i) {
                const size_t wb = (wsrow + srow[i]) * 96 + (w0 >> 1) + (scol[i] >> 1);
                wsc[2 * i] = ws[wb];
                wsc[2 * i + 1] = ws[wb + 1];
            }
        }
    }
    for (int t = NT - 1; t >= 0; --t) {
        const int w0 = t * TW;
        if (t > 0) {
            const int wn = w0 - TW;
#pragma unroll
            for (int i = 0; i < 3; ++i)
                pre[i] = *reinterpret_cast<const float4*>(xrow + (size_t)srow[i] * HW + wn + scol[i]);
            gAn = gbrow[(size_t)gk * HW + wn + gwi];
            g4n = gbrow[(size_t)4 * HW + wn + gwi];
            if constexpr (WS) {
#pragma unroll
                for (int i = 0; i < 3; ++i) {
                    const size_t wb = (wsrow + srow[i]) * 96 + (wn >> 1) + (scol[i] >> 1);
                    wsn[2 * i] = ws[wb];
                    wsn[2 * i + 1] = ws[wb + 1];
                }
            }
        }
        unsigned rr[8];
        if (t < 8) {
#pragma unroll
            for (int r = 0; r < 8; ++r) rr[r] = sstash[t * 8 + r][dl];
        } else if (t == 8) {
#pragma unroll
            for (int r = 0; r < 8; ++r) rr[r] = sv0[r];
        } else if (t == 9) {
#pragma unroll
            for (int r = 0; r < 8; ++r) rr[r] = sv1[r];
        } else if (t == 10) {
#pragma unroll
            for (int r = 0; r < 8; ++r) rr[r] = sv2[r];
        } else {
#pragma unroll
            for (int r = 0; r < 8; ++r) rr[r] = sv3[r];
        }
#pragma unroll
        for (int wk = TW - 1; wk >= 0; --wk) {
            const float g0v = rdlane(gA, wk);
            const float g1v = rdlane(gA, 16 + wk);
            const float g2v = rdlane(gA, 32 + wk);
            const float g3v = rdlane(gA, 48 + wk);
            const float g4v = rdlane(g4r, wk);
            const float cs = xo[dl][wk];
            A = sga_step(A, cs, g0v, g1v, g2v, g3v, g4v, is47, (t == NT - 1 && wk == TW - 1));
            const unsigned u = rr[wk >> 1];
            const float a0 = h2f((unsigned short)((wk & 1) ? (u >> 16) : (u & 0xffffu)));
            if (lane < Dd) xo[lane][wk] = fmaxf(A, a0);
        }
#pragma unroll
        for (int i = 0; i < 3; ++i) {
            float4 v;
            v.x = xo[srow[i]][scol[i] + 0];
            v.y = xo[srow[i]][scol[i] + 1];
            v.z = xo[srow[i]][scol[i] + 2];
            v.w = xo[srow[i]][scol[i] + 3];
            if constexpr (WS) {
                v.x = fmaxf(v.x, h2f((unsigned short)(wsc[2 * i] & 0xffffu)));
                v.y = fmaxf(v.y, h2f((unsigned short)(wsc[2 * i] >> 16)));
                v.z = fmaxf(v.z, h2f((unsigned short)(wsc[2 * i + 1] & 0xffffu)));
                v.w = fmaxf(v.w, h2f((unsigned short)(wsc[2 * i + 1] >> 16)));
            }
            *reinterpret_cast<float4*>(orow + (size_t)srow[i] * HW + w0 + scol[i]) = v;
        }
        if (t > 0) {
#pragma unroll
            for (int i = 0; i < 3; ++i) {
                xo[srow[i]][scol[i] + 0] = pre[i].x;
                xo[srow[i]][scol[i] + 1] = pre[i].y;
                xo[srow[i]][scol[i] + 2] = pre[i].z;
                xo[srow[i]][scol[i] + 3] = pre[i].w;
            }
#pragma unroll
            for (int i = 0; i < 6; ++i) wsc[i] = wsn[i];
            gA = gAn;
            g4r = g4n;
        }
    }
}

// ============================================================================
// H scan, register-resident: lane = w (64 consecutive columns per wave),
// A[48] in registers. No LDS, no barriers, no DPP. d+-1 = static register
// refs; max over d = in-register tree. All global accesses fully coalesced.
// MODE 0: ws[h][d][w] (fp16) = A        (fwd pass writes a2)
// MODE 1: ws = max(ws, A)               (rev pass folds in a3)
// MODE 2: out = max(out, A) fp32        (fallback when ws too small)
// Single-buffered in-place reloads (use-then-reload) keep VGPRs ~165.
// ============================================================================
template <bool REV, int MODE>
__global__ __launch_bounds__(64) void sga_hreg(const float* __restrict__ x,
                                               const float* __restrict__ g,
                                               unsigned short* __restrict__ ws,
                                               float* __restrict__ out) {
    const int c = blockIdx.x / 3;
    const int w = (blockIdx.x % 3) * 64 + threadIdx.x;
    const size_t HW = (size_t)Hh * Ww;

    const float* xb = x + (size_t)c * Dd * HW;            // + d*HW + h*Ww + w
    const float* gb = g + (size_t)c * 5 * HW;             // + k*HW + h*Ww + w
    unsigned short* wsb = ws + (size_t)c * Hh * Dd * Ww;  // + (h*Dd+d)*Ww + w
    float* ob = out + (size_t)c * Dd * HW;                // + d*HW + h*Ww + w

    auto hof = [](int p) { return REV ? (Hh - 1 - p) : p; };

    float A[Dd], xr[Dd], gr[5], gn[5];
    unsigned short hl[Dd];   // MODE1: pending ws values
    float wl[Dd];            // MODE2: pending out values

    // ---- prologue: loads for p=0 (x, prev-values) and g for p=1 ----
    {
        const int h0 = hof(0);
#pragma unroll
        for (int d = 0; d < Dd; ++d) xr[d] = xb[(size_t)d * HW + (size_t)h0 * Ww + w];
        if (MODE == 1) {
#pragma unroll
            for (int d = 0; d < Dd; ++d) hl[d] = wsb[((size_t)h0 * Dd + d) * Ww + w];
        } else if (MODE == 2) {
#pragma unroll
            for (int d = 0; d < Dd; ++d) wl[d] = ob[(size_t)d * HW + (size_t)h0 * Ww + w];
        }
        const int h1 = hof(1);
#pragma unroll
        for (int k = 0; k < 5; ++k) gr[k] = gb[(size_t)k * HW + (size_t)h1 * Ww + w];
    }

    // ---- peeled p = 0: A = c; reload x for p=1 ----
    {
        const int h0 = hof(0);
        const int h1 = hof(1);
#pragma unroll
        for (int d = 0; d < Dd; ++d) {
            A[d] = xr[d];
            if (MODE == 0)
                wsb[((size_t)h0 * Dd + d) * Ww + w] = (unsigned short)f2h(A[d]);
            xr[d] = xb[(size_t)d * HW + (size_t)h1 * Ww + w];
        }
    }

    // ---- main loop p = 1..95 ----
    for (int p = 1; p < Hh; ++p) {
        const int h = hof(p);
        const int hn = hof(p + 1);       // used only when p+1 < Hh
        const bool notlast = (p + 1 < Hh);

        // issue g loads for p+1
        if (notlast) {
#pragma unroll
            for (int k = 0; k < 5; ++k) gn[k] = gb[(size_t)k * HW + (size_t)hn * Ww + w];
        }

        // flush step p-1 (A still holds it), then reload pending vals for step p
        if (MODE == 1) {
            const int hm = hof(p - 1);
#pragma unroll
            for (int d = 0; d < Dd; ++d) {
                const float m = fmaxf(A[d], h2f(hl[d]));
                wsb[((size_t)hm * Dd + d) * Ww + w] = (unsigned short)f2h(m);
                hl[d] = wsb[((size_t)h * Dd + d) * Ww + w];
            }
        } else if (MODE == 2) {
            const int hm = hof(p - 1);
#pragma unroll
            for (int d = 0; d < Dd; ++d) {
                ob[(size_t)d * HW + (size_t)hm * Ww + w] = fmaxf(A[d], wl[d]);
                wl[d] = ob[(size_t)d * HW + (size_t)h * Ww + w];
            }
        }

        // M = max_d A[d] (in-register tree, depth ~6)
        float t0[24];
#pragma unroll
        for (int i = 0; i < 24; ++i) t0[i] = fmaxf(A[2 * i], A[2 * i + 1]);
#pragma unroll
        for (int i = 0; i < 12; ++i) t0[i] = fmaxf(t0[i], t0[i + 12]);
#pragma unroll
        for (int i = 0; i < 6; ++i) t0[i] = fmaxf(t0[i], t0[i + 6]);
#pragma unroll
        for (int i = 0; i < 3; ++i) t0[i] = fmaxf(t0[i], t0[i + 3]);
        const float M = fmaxf(t0[0], fmaxf(t0[1], t0[2]));

        // recurrence over d (static register refs; edge-clamped)
        float pm = A[0];
#pragma unroll
        for (int d = 0; d < Dd; ++d) {
            const float cur = A[d];
            const float np = (d < Dd - 1) ? A[d + 1] : cur;
            A[d] = gr[0] * xr[d] + gr[1] * cur + gr[2] * pm + gr[3] * np + gr[4] * M;
            pm = cur;
            if (MODE == 0)
                wsb[((size_t)h * Dd + d) * Ww + w] = (unsigned short)f2h(A[d]);
            if (notlast) xr[d] = xb[(size_t)d * HW + (size_t)hn * Ww + w];
        }
#pragma unroll
        for (int k = 0; k < 5; ++k) gr[k] = gn[k];
    }

    // ---- epilogue: flush step 95 ----
    if (MODE == 1) {
        const int hm = hof(Hh - 1);
#pragma unroll
        for (int d = 0; d < Dd; ++d) {
            const float m = fmaxf(A[d], h2f(hl[d]));
            wsb[((size_t)hm * Dd + d) * Ww + w] = (unsigned short)f2h(m);
        }
    } else if (MODE == 2) {
        const int hm = hof(Hh - 1);
#pragma unroll
        for (int d = 0; d < Dd; ++d)
            ob[(size_t)d * HW + (size_t)hm * Ww + w] = fmaxf(A[d], wl[d]);
    }
}

extern "C" void kernel_launch(void* const* d_in, const int* in_sizes, int n_in,
                              void* d_out, int out_size, void* d_ws, size_t ws_size,
                              hipStream_t stream) {
    const float* x  = (const float*)d_in[0];
    const float* g0 = (const float*)d_in[1];
    const float* g1 = (const float*)d_in[2];
    const float* g2 = (const float*)d_in[3];
    const float* g3 = (const float*)d_in[4];
    float* out = (float*)d_out;

    const size_t WSNEED = (size_t)Cc * Hh * Dd * Ww * 2;  // 56.6 MB fp16
    if (ws_size >= WSNEED) {
        // H fwd: ws = a2 (fp16). H rev: ws = max(ws, a3). W: out = max(a0,a1,ws).
        sga_hreg<false, 0><<<Cc * 3, 64, 0, stream>>>(x, g2, (unsigned short*)d_ws, out);
        sga_hreg<true,  1><<<Cc * 3, 64, 0, stream>>>(x, g3, (unsigned short*)d_ws, out);
        sga_w4<true><<<Cc * Hh, 64, 0, stream>>>(x, g0, g1, out, (const unsigned*)d_ws);
    } else {
        // fallback: W writes out = max(a0,a1); H dirs RMW out in fp32, serialized.
        sga_w4<false><<<Cc * Hh, 64, 0, stream>>>(x, g0, g1, out, nullptr);
        sga_hreg<false, 2><<<Cc * 3, 64, 0, stream>>>(x, g2, nullptr, out);
        sga_hreg<true,  2><<<Cc * 3, 64, 0, stream>>>(x, g3, nullptr, out);
    }
}

// Round 8
// 272.645 us; speedup vs baseline: 2.0873x; 2.0873x over previous
//
#include <hip/hip_runtime.h>

// Problem constants (B=1)
constexpr int Cc = 32;
constexpr int Dd = 48;
constexpr int Hh = 96;
constexpr int Ww = 192;
constexpr int TW = 16;           // W-kernel tile width
constexpr int NT = Ww / TW;      // 12 tiles
constexpr float NEGBIG = -3.402823466e+38f;

// ---- DPP helpers ------------------------------------------------------------
// NOTE: must use __builtin_amdgcn_update_dpp (not inline asm) — the compiler's
// hazard recognizer inserts the required VALU->DPP wait states only for
// compiler-known DPP ops. Inline-asm DPP caused silent corruption (round 3).
template <int CTRL, int RM>
__device__ __forceinline__ float dppmov(float v) {
    int i = __builtin_bit_cast(int, v);
    int r = __builtin_amdgcn_update_dpp(i, i, CTRL, RM, 0xF, false);
    return __builtin_bit_cast(float, r);
}

__device__ __forceinline__ float rdlane(float v, int idx) {
    int r = __builtin_amdgcn_readlane(__builtin_bit_cast(int, v), idx);
    return __builtin_bit_cast(float, r);
}

__device__ __forceinline__ unsigned f2h(float v) {
    return (unsigned)__builtin_bit_cast(unsigned short, (_Float16)v);
}
__device__ __forceinline__ float h2f(unsigned short u) {
    return (float)__builtin_bit_cast(_Float16, u);
}

// Max over lanes 0..47, broadcast. Row-confined: junk in lanes 48..63 never
// enters the reduction.
__device__ __forceinline__ float wave_max48(float v) {
    v = fmaxf(v, dppmov<0x111, 0xF>(v));   // row_shr:1
    v = fmaxf(v, dppmov<0x112, 0xF>(v));   // row_shr:2
    v = fmaxf(v, dppmov<0x114, 0xF>(v));   // row_shr:4
    v = fmaxf(v, dppmov<0x118, 0xF>(v));   // row_shr:8
    v = fmaxf(v, dppmov<0x142, 0x2>(v));   // row_bcast:15 -> row1: lane31=max(0..31)
    v = fmaxf(v, dppmov<0x143, 0x4>(v));   // row_bcast:31 -> row2: lane47=max(0..47)
    return rdlane(v, 47);
}

// One SGA step (lane = d). Lanes >= 48 compute garbage that never propagates
// back into lanes 0..47.
__device__ __forceinline__ float sga_step(float A, float cs, float g0v, float g1v, float g2v,
                                          float g3v, float g4v, bool is47, bool first) {
    float dm1 = dppmov<0x138, 0xF>(A);             // wave_shr:1, lane0 keeps own
    float dp1 = dppmov<0x130, 0xF>(A);             // wave_shl:1
    dp1 = is47 ? A : dp1;                          // d+1 clamp at d=47
    float mx = wave_max48(A);
    float r = g0v * cs + g1v * A + g2v * dm1 + g3v * dp1 + g4v * mx;
    return first ? cs : r;
}

// ============================================================================
// W-pair kernel (unchanged from round 6): fwd scan (ga) stashes a0 fp16
// on-chip (LDS tiles 0-7, static reg banks 8-11), rev scan (gb) combines
// (+ ws), writes out once. 1 wave/block, no barriers, 15.6 KB LDS.
// ============================================================================
template <bool WS>
__global__ __launch_bounds__(64, 4) void sga_w4(const float* __restrict__ x,
                                                const float* __restrict__ ga,
                                                const float* __restrict__ gb,
                                                float* __restrict__ out,
                                                const unsigned* __restrict__ ws) {
    __shared__ unsigned sstash[64][Dd];   // tiles 0..7, [t*8+r][lane]
    __shared__ float xo[Dd][TW + 1];      // x tile / flush tile

    const int bid = blockIdx.x;
    const int c = bid / Hh;
    const int h = bid - c * Hh;
    const int lane = threadIdx.x;
    const size_t HW = (size_t)Hh * Ww;

    const float* xrow = x + (size_t)c * Dd * HW + (size_t)h * Ww;
    const float* garow = ga + (size_t)c * 5 * HW + (size_t)h * Ww;
    const float* gbrow = gb + (size_t)c * 5 * HW + (size_t)h * Ww;
    float* orow = out + (size_t)c * Dd * HW + (size_t)h * Ww;
    const size_t wsrow = ((size_t)c * Hh + h) * Dd;   // in 96-u32 rows

    const int dl = (lane < Dd) ? lane : (Dd - 1);
    const bool is47 = (lane == Dd - 1);

    int srow[3], scol[3];
#pragma unroll
    for (int i = 0; i < 3; ++i) {
        const int e4 = lane + i * 64;
        srow[i] = e4 >> 2;
        scol[i] = (e4 & 3) * 4;
    }
    const int gk = lane >> 4;
    const int gwi = lane & 15;

    float4 pre[3];
    float gA, g4r, gAn = 0.f, g4n = 0.f;
    unsigned tr[8];
    unsigned sv0[8], sv1[8], sv2[8], sv3[8];

    {
#pragma unroll
        for (int i = 0; i < 3; ++i)
            pre[i] = *reinterpret_cast<const float4*>(xrow + (size_t)srow[i] * HW + scol[i]);
        gA = garow[(size_t)gk * HW + gwi];
        g4r = garow[(size_t)4 * HW + gwi];
#pragma unroll
        for (int i = 0; i < 3; ++i) {
            xo[srow[i]][scol[i] + 0] = pre[i].x;
            xo[srow[i]][scol[i] + 1] = pre[i].y;
            xo[srow[i]][scol[i] + 2] = pre[i].z;
            xo[srow[i]][scol[i] + 3] = pre[i].w;
        }
    }

    float A = NEGBIG;

    // forward: a0 -> on-chip fp16 stash
    for (int t = 0; t < NT; ++t) {
        if (t + 1 < NT) {
            const int wn = (t + 1) * TW;
#pragma unroll
            for (int i = 0; i < 3; ++i)
                pre[i] = *reinterpret_cast<const float4*>(xrow + (size_t)srow[i] * HW + wn + scol[i]);
            gAn = garow[(size_t)gk * HW + wn + gwi];
            g4n = garow[(size_t)4 * HW + wn + gwi];
        }
#pragma unroll
        for (int wk = 0; wk < TW; ++wk) {
            const float g0v = rdlane(gA, wk);
            const float g1v = rdlane(gA, 16 + wk);
            const float g2v = rdlane(gA, 32 + wk);
            const float g3v = rdlane(gA, 48 + wk);
            const float g4v = rdlane(g4r, wk);
            const float cs = xo[dl][wk];
            A = sga_step(A, cs, g0v, g1v, g2v, g3v, g4v, is47, (t == 0 && wk == 0));
            const unsigned hu = f2h(A);
            if ((wk & 1) == 0) tr[wk >> 1] = hu;
            else tr[wk >> 1] |= hu << 16;
        }
        if (t < 8) {
            if (lane < Dd) {
#pragma unroll
                for (int r = 0; r < 8; ++r) sstash[t * 8 + r][lane] = tr[r];
            }
        } else if (t == 8) {
#pragma unroll
            for (int r = 0; r < 8; ++r) sv0[r] = tr[r];
        } else if (t == 9) {
#pragma unroll
            for (int r = 0; r < 8; ++r) sv1[r] = tr[r];
        } else if (t == 10) {
#pragma unroll
            for (int r = 0; r < 8; ++r) sv2[r] = tr[r];
        } else {
#pragma unroll
            for (int r = 0; r < 8; ++r) sv3[r] = tr[r];
        }
        if (t + 1 < NT) {
#pragma unroll
            for (int i = 0; i < 3; ++i) {
                xo[srow[i]][scol[i] + 0] = pre[i].x;
                xo[srow[i]][scol[i] + 1] = pre[i].y;
                xo[srow[i]][scol[i] + 2] = pre[i].z;
                xo[srow[i]][scol[i] + 3] = pre[i].w;
            }
            gA = gAn;
            g4r = g4n;
        }
    }

    // reverse + combine + single write
    A = NEGBIG;
    unsigned wsc[6], wsn[6];
    {
        const int w0 = (NT - 1) * TW;
        gA = gbrow[(size_t)gk * HW + w0 + gwi];
        g4r = gbrow[(size_t)4 * HW + w0 + gwi];
        if constexpr (WS) {
#pragma unroll
            for (int i = 0; i < 3; ++i) {
                const size_t wb = (wsrow + srow[i]) * 96 + (w0 >> 1) + (scol[i] >> 1);
                wsc[2 * i] = ws[wb];
                wsc[2 * i + 1] = ws[wb + 1];
            }
        }
    }
    for (int t = NT - 1; t >= 0; --t) {
        const int w0 = t * TW;
        if (t > 0) {
            const int wn = w0 - TW;
#pragma unroll
            for (int i = 0; i < 3; ++i)
                pre[i] = *reinterpret_cast<const float4*>(xrow + (size_t)srow[i] * HW + wn + scol[i]);
            gAn = gbrow[(size_t)gk * HW + wn + gwi];
            g4n = gbrow[(size_t)4 * HW + wn + gwi];
            if constexpr (WS) {
#pragma unroll
                for (int i = 0; i < 3; ++i) {
                    const size_t wb = (wsrow + srow[i]) * 96 + (wn >> 1) + (scol[i] >> 1);
                    wsn[2 * i] = ws[wb];
                    wsn[2 * i + 1] = ws[wb + 1];
                }
            }
        }
        unsigned rr[8];
        if (t < 8) {
#pragma unroll
            for (int r = 0; r < 8; ++r) rr[r] = sstash[t * 8 + r][dl];
        } else if (t == 8) {
#pragma unroll
            for (int r = 0; r < 8; ++r) rr[r] = sv0[r];
        } else if (t == 9) {
#pragma unroll
            for (int r = 0; r < 8; ++r) rr[r] = sv1[r];
        } else if (t == 10) {
#pragma unroll
            for (int r = 0; r < 8; ++r) rr[r] = sv2[r];
        } else {
#pragma unroll
            for (int r = 0; r < 8; ++r) rr[r] = sv3[r];
        }
#pragma unroll
        for (int wk = TW - 1; wk >= 0; --wk) {
            const float g0v = rdlane(gA, wk);
            const float g1v = rdlane(gA, 16 + wk);
            const float g2v = rdlane(gA, 32 + wk);
            const float g3v = rdlane(gA, 48 + wk);
            const float g4v = rdlane(g4r, wk);
            const float cs = xo[dl][wk];
            A = sga_step(A, cs, g0v, g1v, g2v, g3v, g4v, is47, (t == NT - 1 && wk == TW - 1));
            const unsigned u = rr[wk >> 1];
            const float a0 = h2f((unsigned short)((wk & 1) ? (u >> 16) : (u & 0xffffu)));
            if (lane < Dd) xo[lane][wk] = fmaxf(A, a0);
        }
#pragma unroll
        for (int i = 0; i < 3; ++i) {
            float4 v;
            v.x = xo[srow[i]][scol[i] + 0];
            v.y = xo[srow[i]][scol[i] + 1];
            v.z = xo[srow[i]][scol[i] + 2];
            v.w = xo[srow[i]][scol[i] + 3];
            if constexpr (WS) {
                v.x = fmaxf(v.x, h2f((unsigned short)(wsc[2 * i] & 0xffffu)));
                v.y = fmaxf(v.y, h2f((unsigned short)(wsc[2 * i] >> 16)));
                v.z = fmaxf(v.z, h2f((unsigned short)(wsc[2 * i + 1] & 0xffffu)));
                v.w = fmaxf(v.w, h2f((unsigned short)(wsc[2 * i + 1] >> 16)));
            }
            *reinterpret_cast<float4*>(orow + (size_t)srow[i] * HW + w0 + scol[i]) = v;
        }
        if (t > 0) {
#pragma unroll
            for (int i = 0; i < 3; ++i) {
                xo[srow[i]][scol[i] + 0] = pre[i].x;
                xo[srow[i]][scol[i] + 1] = pre[i].y;
                xo[srow[i]][scol[i] + 2] = pre[i].z;
                xo[srow[i]][scol[i] + 3] = pre[i].w;
            }
#pragma unroll
            for (int i = 0; i < 6; ++i) wsc[i] = wsn[i];
            gA = gAn;
            g4r = g4n;
        }
    }
}

// ============================================================================
// H-pair kernel h5 = round-5 h3 schedule (KH2=4, 24 barriers — the proven
// fast variant) + fp16 osb + fp16 write-only ws output (WS=true).
// Block = 4 columns x 2 dirs = 8 waves (512 thr). First 48 windows stash
// fp16; last 48 combine with opposite stash. ~61 KB LDS -> 2 blocks/CU.
// WS=false fallback: fp32 RMW on out.
// ============================================================================
constexpr int WT2 = 4;
constexpr int KH2 = 4;
constexpr int NP2 = Hh / KH2;     // 24 periods
constexpr int HALF = NP2 / 2;     // 12

template <bool WS>
__global__ __launch_bounds__(512, 2) void sga_h5(const float* __restrict__ x,
                                                 const float* __restrict__ gf,
                                                 const float* __restrict__ gr,
                                                 float* __restrict__ out,
                                                 unsigned* __restrict__ ws) {
    __shared__ unsigned short stash[WT2][2][Hh / 2][Dd];   // 36864 B
    __shared__ float xs[2][2][KH2][Dd][WT2 + 1];           // 15360 B
    __shared__ unsigned short osb[2][2][KH2][Dd][6];       // 4608 B (u32-readable)
    __shared__ float gs[2][2][KH2][WT2][8];                // 4096 B
    // total 60928 B -> 2 blocks/CU

    // quad XCD swizzle: 4 sibling blocks covering one 64B line-span share bid%8.
    const int xcd = blockIdx.x & 7;
    const int within = blockIdx.x >> 3;          // 0..191
    const int L = xcd * 192 + within;
    const int quad = L >> 2, sub = L & 3;
    const int c = quad / 12;
    const int wq = quad % 12;
    const int w0 = wq * 16 + sub * 4;

    const int tid = threadIdx.x;
    const int lane = tid & 63;
    const int wv = tid >> 6;            // 0..7
    const int col = wv >> 1;            // 0..3
    const int dir = wv & 1;             // 0=fwd(h asc), 1=rev(h desc)
    const size_t HW = (size_t)Hh * Ww;

    const float* xb = x + (size_t)c * Dd * HW;
    const float* gfb = gf + (size_t)c * 5 * HW;
    const float* grb = gr + (size_t)c * 5 * HW;
    float* ob = out + (size_t)c * Dd * HW;

    const int dl = (lane < Dd) ? lane : (Dd - 1);
    const bool is47 = (lane == Dd - 1);

    // x staging decomposition: idx = tid + j*512 over [2cu][4hp][48d][4w] = 1536
    int w_[3], d_[3], hp_[3], cu_[3];
    size_t xoff_[3];
#pragma unroll
    for (int j = 0; j < 3; ++j) {
        const int idx = tid + j * 512;
        w_[j] = idx & 3;
        const int t = idx >> 2;
        d_[j] = t % Dd;
        const int t2 = t / Dd;
        hp_[j] = t2 & 3;
        cu_[j] = t2 >> 2;
        xoff_[j] = (size_t)d_[j] * HW + (w0 + w_[j]);
    }
    // g staging (tid < 160): [2cu][4hp][5k][4w]
    const int gw_ = tid & 3;
    const int gk_ = (tid >> 2) % 5;
    const int ghc = (tid >> 2) / 5;       // 0..7
    const int ghp_ = ghc & 3;
    const int gcu_ = ghc >> 2;
    const bool gst = tid < 160;
    // WS flush mapping: idx = tid + j*512 over [2cu][4hp][48d][2u32] = 768
    int fu_[2], fd_[2], fhp_[2], fcu_[2];
    bool fval_[2];
#pragma unroll
    for (int j = 0; j < 2; ++j) {
        int idx = tid + j * 512;
        fval_[j] = idx < 768;
        if (idx >= 768) idx = 767;
        fu_[j] = idx & 1;
        const int t = idx >> 1;
        fd_[j] = t % Dd;
        const int r = t / Dd;
        fhp_[j] = r & 3;
        fcu_[j] = r >> 2;
    }

    auto hofs = [&](int cur, int P, int hp) -> int {
        const int p = P * KH2 + hp;
        return cur ? (Hh - 1 - p) : p;
    };

    float xr_[3], grg = 0.f;
    float orr[2][3];   // fallback (WS=false) only

    // prologue: stage period 0 into buf 0
    {
#pragma unroll
        for (int j = 0; j < 3; ++j) xr_[j] = xb[xoff_[j] + (size_t)hofs(cu_[j], 0, hp_[j]) * Ww];
        if (gst) {
            const float* gp = gcu_ ? grb : gfb;
            grg = gp[(size_t)gk_ * HW + (size_t)hofs(gcu_, 0, ghp_) * Ww + (w0 + gw_)];
        }
#pragma unroll
        for (int j = 0; j < 3; ++j) xs[0][cu_[j]][hp_[j]][d_[j]][w_[j]] = xr_[j];
        if (gst) gs[0][gcu_][ghp_][gw_][gk_] = grg;
    }
    __syncthreads();

    float A = NEGBIG;

#pragma unroll 2
    for (int p = 0; p < NP2; ++p) {
        const int pb = p & 1;

        // (1) issue staging loads for period p+1
        if (p + 1 < NP2) {
#pragma unroll
            for (int j = 0; j < 3; ++j)
                xr_[j] = xb[xoff_[j] + (size_t)hofs(cu_[j], p + 1, hp_[j]) * Ww];
            if (gst) {
                const float* gp = gcu_ ? grb : gfb;
                grg = gp[(size_t)gk_ * HW + (size_t)hofs(gcu_, p + 1, ghp_) * Ww + (w0 + gw_)];
            }
        }
        // (2) fallback only: issue out-reads for THIS period (flushed next period)
        if constexpr (!WS) {
            if (p >= HALF) {
#pragma unroll
                for (int j = 0; j < 3; ++j)
                    orr[pb][j] = ob[xoff_[j] + (size_t)hofs(cu_[j], p, hp_[j]) * Ww];
            }
        }

        // (3) compute KH2 windows
#pragma unroll
        for (int hp = 0; hp < KH2; ++hp) {
            const int q = p * KH2 + hp;
            const float cs = xs[pb][dir][hp][dl][col];
            const float* gbase = &gs[pb][dir][hp][col][0];
            const float4 g03 = *reinterpret_cast<const float4*>(gbase);
            const float g4 = gbase[4];
            A = sga_step(A, cs, g03.x, g03.y, g03.z, g03.w, g4, is47, q == 0);
            if (q < Hh / 2) {
                if (lane < Dd) stash[col][dir][q][lane] = (unsigned short)f2h(A);
            } else {
                const float s = h2f(stash[col][dir ^ 1][Hh - 1 - q][dl]);
                const float o = fmaxf(A, s);
                if (lane < Dd) osb[pb][dir][hp][lane][col] = (unsigned short)f2h(o);
            }
        }

        // (4) flush period p-1
        if (p > HALF) {
            if constexpr (WS) {
#pragma unroll
                for (int j = 0; j < 2; ++j) {
                    if (fval_[j]) {
                        const unsigned* op =
                            reinterpret_cast<const unsigned*>(&osb[pb ^ 1][fcu_[j]][fhp_[j]][fd_[j]][0]);
                        const unsigned v = op[fu_[j]];
                        const int hh = hofs(fcu_[j], p - 1, fhp_[j]);
                        ws[(((size_t)c * Hh + hh) * Dd + fd_[j]) * 96 + (w0 >> 1) + fu_[j]] = v;
                    }
                }
            } else {
#pragma unroll
                for (int j = 0; j < 3; ++j) {
                    const float v = fmaxf(h2f(osb[pb ^ 1][cu_[j]][hp_[j]][d_[j]][w_[j]]),
                                          orr[pb ^ 1][j]);
                    ob[xoff_[j] + (size_t)hofs(cu_[j], p - 1, hp_[j]) * Ww] = v;
                }
            }
        }

        // (5) commit staged regs for p+1
        if (p + 1 < NP2) {
#pragma unroll
            for (int j = 0; j < 3; ++j) xs[pb ^ 1][cu_[j]][hp_[j]][d_[j]][w_[j]] = xr_[j];
            if (gst) gs[pb ^ 1][gcu_][ghp_][gw_][gk_] = grg;
        }
        __syncthreads();
    }

    // epilogue: flush last period (p = NP2-1, pb = 1)
    if constexpr (WS) {
#pragma unroll
        for (int j = 0; j < 2; ++j) {
            if (fval_[j]) {
                const unsigned* op =
                    reinterpret_cast<const unsigned*>(&osb[1][fcu_[j]][fhp_[j]][fd_[j]][0]);
                const unsigned v = op[fu_[j]];
                const int hh = hofs(fcu_[j], NP2 - 1, fhp_[j]);
                ws[(((size_t)c * Hh + hh) * Dd + fd_[j]) * 96 + (w0 >> 1) + fu_[j]] = v;
            }
        }
    } else {
#pragma unroll
        for (int j = 0; j < 3; ++j) {
            const float v = fmaxf(h2f(osb[1][cu_[j]][hp_[j]][d_[j]][w_[j]]), orr[1][j]);
            ob[xoff_[j] + (size_t)hofs(cu_[j], NP2 - 1, hp_[j]) * Ww] = v;
        }
    }
}

extern "C" void kernel_launch(void* const* d_in, const int* in_sizes, int n_in,
                              void* d_out, int out_size, void* d_ws, size_t ws_size,
                              hipStream_t stream) {
    const float* x  = (const float*)d_in[0];
    const float* g0 = (const float*)d_in[1];
    const float* g1 = (const float*)d_in[2];
    const float* g2 = (const float*)d_in[3];
    const float* g3 = (const float*)d_in[4];
    float* out = (float*)d_out;

    const size_t WSNEED = (size_t)Cc * Hh * Dd * Ww * 2;  // 56.6 MB fp16
    if (ws_size >= WSNEED) {
        // H pair: ws = max(a2,a3) fp16 (write-only). W pair: out = max(a0,a1,ws).
        sga_h5<true><<<Cc * (Ww / (WT2 * 4)) * 4, 512, 0, stream>>>(x, g2, g3, out, (unsigned*)d_ws);
        sga_w4<true><<<Cc * Hh, 64, 0, stream>>>(x, g0, g1, out, (const unsigned*)d_ws);
    } else {
        // fallback: W writes out = max(a0,a1); H RMWs out with max(a2,a3) in fp32.
        sga_w4<false><<<Cc * Hh, 64, 0, stream>>>(x, g0, g1, out, nullptr);
        sga_h5<false><<<Cc * (Ww / (WT2 * 4)) * 4, 512, 0, stream>>>(x, g2, g3, out, nullptr);
    }
}